// Round 13
// baseline (40.030 us; speedup 1.0000x reference)
//
#include <hip/hip_runtime.h>

// SimpleUnsharedPatchScorer — register-run reduction, image-paired waves.
// t = i*9408 + j*588 + c*196 + h*14 + w  (i,j in [0,16), c in [0,3), h,w in [0,14))
// value at t: x[b, c, 16h+i, 16w+j];  out bin p = t/768.
// R11 post-mortem: 128B lane map neutral vs R9 -> revert to R9 map. New theory: 150MB
// of wlay re-reads (294KB x 512 blocks, L2-thrashed by the x stream) contend on the
// L2-fill path. R12: block = (img-pair, hh, c), 768 blocks x 448thr; each wave = one
// (c,h) tile x 2 images, weight float4 loaded once per pair -> 75MB weight traffic.

#define NPATCH 196
#define NF4IMG 37632     // float4s per image = 150528/4
#define BSTR   197       // LDS bin row stride

// prep (same as R9): wlay[((c*14+h)*14+w)*256 + i*16 + jj] = weight[t]; bias-init out.
__global__ __launch_bounds__(256) void prep_kernel(
    const float* __restrict__ weight,
    const float* __restrict__ bias,
    float* __restrict__ wlay,
    float* __restrict__ out)
{
    const int bid = blockIdx.x;
    if (bid < 147) {                          // 147*256*4 == 150528 weights
        const int t4 = bid * 256 + threadIdx.x;
        const float4 wv = ((const float4*)weight)[t4];
        const float wt[4] = {wv.x, wv.y, wv.z, wv.w};
        #pragma unroll
        for (int u = 0; u < 4; ++u) {
            const int t    = 4 * t4 + u;
            const int i    = t / 9408;
            const int rem  = t - i * 9408;
            const int jj   = rem / 588;
            const int rem2 = rem - jj * 588;
            const int c    = rem2 / 196;
            const int rem3 = rem2 - c * 196;
            const int h    = rem3 / 14;
            const int w    = rem3 - h * 14;
            wlay[((c * 14 + h) * 14 + w) * 256 + i * 16 + jj] = wt[u];
        }
    } else {                                  // 49*256*4 == 50176 == 256*196 bias-init
        const int g4 = (bid - 147) * 256 + threadIdx.x;
        const int g  = 4 * g4;
        float4 o;
        o.x = bias[(g + 0) % NPATCH];
        o.y = bias[(g + 1) % NPATCH];
        o.z = bias[(g + 2) % NPATCH];
        o.w = bias[(g + 3) % NPATCH];
        ((float4*)out)[g4] = o;
    }
}

__global__ __launch_bounds__(448) void run_kernel(
    const float* __restrict__ x,     // [256,3,224,224]
    const float* __restrict__ wlay,  // permuted weights (602112 floats)
    float* __restrict__ out)         // [256,196], bias pre-loaded
{
    __shared__ float bins[2 * BSTR];          // per-image bin rows (shared by 7 waves)
    const int tid  = threadIdx.x;
    const int r    = blockIdx.x & 255;
    const int c    = blockIdx.x >> 8;         // channel 0..2
    const int hh   = r & 1;                   // h half
    const int b0   = (r >> 1) * 2;            // image pair base
    const int wv   = tid >> 6;                // wave 0..6
    const int lane = tid & 63;
    const int i    = lane >> 2;
    const int j4   = lane & 3;                // j = 4*j4 + dj
    const int h    = hh * 7 + wv;
    const int tile = c * 14 + h;

    for (int k = tid; k < 2 * BSTR; k += 448) bins[k] = 0.0f;
    __syncthreads();

    const float4* __restrict__ x40 = (const float4*)x + (size_t)b0 * NF4IMG
                                     + c * 12544 + (16 * h + i) * 56 + j4;
    const float4* __restrict__ x41 = x40 + NF4IMG;
    const float4* __restrict__ w4  = (const float4*)wlay + tile * 896 + i * 4 + j4;

    int p0[4], ws_[4];
    #pragma unroll
    for (int u = 0; u < 4; ++u) {
        const int jj = 4 * j4 + u;
        const int t0 = i * 9408 + jj * 588 + c * 196 + h * 14;
        p0[u]  = t0 / 768;
        ws_[u] = 768 * (p0[u] + 1) - t0;      // w >= ws_ -> bin p0+1 (ws_=14 => no split)
    }

    float accA0[4] = {0.f, 0.f, 0.f, 0.f}, accB0[4] = {0.f, 0.f, 0.f, 0.f};
    float accA1[4] = {0.f, 0.f, 0.f, 0.f}, accB1[4] = {0.f, 0.f, 0.f, 0.f};

    #pragma unroll
    for (int w = 0; w < 14; ++w) {
        const float4 wv_ = w4[64 * w];        // one weight load serves both images
        const float4 xv0 = x40[4 * w];
        const float4 xv1 = x41[4 * w];
        const float wsv[4] = {wv_.x, wv_.y, wv_.z, wv_.w};
        const float xs0[4] = {xv0.x, xv0.y, xv0.z, xv0.w};
        const float xs1[4] = {xv1.x, xv1.y, xv1.z, xv1.w};
        #pragma unroll
        for (int u = 0; u < 4; ++u) {
            const float sel = (w < ws_[u]) ? 1.0f : 0.0f;
            const float v0  = xs0[u] * wsv[u];
            const float v1  = xs1[u] * wsv[u];
            accA0[u] = fmaf(v0, sel, accA0[u]);
            accB0[u] = fmaf(v0, 1.0f - sel, accB0[u]);
            accA1[u] = fmaf(v1, sel, accA1[u]);
            accB1[u] = fmaf(v1, 1.0f - sel, accB1[u]);
        }
    }

    #pragma unroll
    for (int u = 0; u < 4; ++u) {
        unsafeAtomicAdd(&bins[p0[u]], accA0[u]);                   // ds_add_f32, img 0
        unsafeAtomicAdd(&bins[BSTR + p0[u]], accA1[u]);            // img 1
        if (ws_[u] < 14) {
            unsafeAtomicAdd(&bins[p0[u] + 1], accB0[u]);           // rare split (~1.7%)
            unsafeAtomicAdd(&bins[BSTR + p0[u] + 1], accB1[u]);
        }
    }
    __syncthreads();

    // one device atomic per (block, img, p): 768 * 392 ~= 301K total
    for (int k = tid; k < 2 * NPATCH; k += 448) {
        const int img = k / NPATCH;
        const int p   = k - img * NPATCH;
        unsafeAtomicAdd(&out[(b0 + img) * NPATCH + p], bins[img * BSTR + p]);
    }
}

extern "C" void kernel_launch(void* const* d_in, const int* in_sizes, int n_in,
                              void* d_out, int out_size, void* d_ws, size_t ws_size,
                              hipStream_t stream) {
    const float* x      = (const float*)d_in[0];
    const float* weight = (const float*)d_in[1];
    const float* bias   = (const float*)d_in[2];
    float* out          = (float*)d_out;
    float* wlay         = (float*)d_ws;      // 602112 bytes

    prep_kernel<<<196, 256, 0, stream>>>(weight, bias, wlay, out);
    run_kernel<<<768, 448, 0, stream>>>(x, wlay, out);
}